// Round 1
// baseline (1355.452 us; speedup 1.0000x reference)
//
#include <hip/hip_runtime.h>
#include <hip/hip_bf16.h>

typedef __attribute__((ext_vector_type(8))) short bf16x8;
typedef __attribute__((ext_vector_type(4))) float f32x4;

#define BATCH 8192
#define D_IN 1024
#define N_H 2048
#define N_CLS 1000
#define BN_EPS 1e-5f

__device__ __forceinline__ f32x4 zero4() { f32x4 z; z.x = 0.f; z.y = 0.f; z.z = 0.f; z.w = 0.f; return z; }

__device__ __forceinline__ unsigned short f2b(float x) {
    unsigned u = __float_as_uint(x);
    u += 0x7fff + ((u >> 16) & 1);   // round-to-nearest-even bf16
    return (unsigned short)(u >> 16);
}

__device__ __forceinline__ ushort4 f2b4(float4 f) {
    ushort4 o; o.x = f2b(f.x); o.y = f2b(f.y); o.z = f2b(f.z); o.w = f2b(f.w); return o;
}

__device__ __forceinline__ void async16(const void* g, void* l) {
    __builtin_amdgcn_global_load_lds((const __attribute__((address_space(1))) void*)g,
                                     (__attribute__((address_space(3))) void*)l, 16, 0, 0);
}

// Wl (1000x2048) -> bf16 padded to (1024x2048)
__global__ void cvt_wl(const float4* __restrict__ in, ushort4* __restrict__ out) {
    long i = (long)blockIdx.x * 256 + threadIdx.x;
    int j = (int)(i >> 9);
    ushort4 o; o.x = 0; o.y = 0; o.z = 0; o.w = 0;
    if (j < N_CLS) o = f2b4(in[i]);
    out[i] = o;
}

// ---------------- reductions ----------------
__device__ __forceinline__ float block_sum(float v, float* red) {
    #pragma unroll
    for (int off = 32; off > 0; off >>= 1) v += __shfl_down(v, off);
    __syncthreads();
    if ((threadIdx.x & 63) == 0) red[threadIdx.x >> 6] = v;
    __syncthreads();
    return red[0] + red[1] + red[2] + red[3];
}

// per-n: bf16 convert mu,v + msq[n]=mu.mu + c[n*4+k]=mu.v_k (fused cvt+dots, float4)
__global__ void prep_nv(const float4* __restrict__ mu, const float4* __restrict__ v,
                        ushort4* __restrict__ mu_bf, ushort4* __restrict__ v_bf,
                        float* __restrict__ msq, float* __restrict__ c, int D4) {
    __shared__ float red[4];
    int n = blockIdx.x, tid = threadIdx.x;
    const float4* m = mu + (long)n * D4;
    const float4* vv = v + (long)n * 4 * D4;
    ushort4* mb = mu_bf + (long)n * D4;
    ushort4* vb = v_bf + (long)n * 4 * D4;
    float sm = 0, s0 = 0, s1 = 0, s2 = 0, s3 = 0;
    for (int d = tid; d < D4; d += 256) {
        float4 mm = m[d];
        mb[d] = f2b4(mm);
        sm += mm.x * mm.x + mm.y * mm.y + mm.z * mm.z + mm.w * mm.w;
        float4 w0 = vv[d], w1 = vv[D4 + d], w2 = vv[2 * D4 + d], w3 = vv[3 * D4 + d];
        vb[d] = f2b4(w0); vb[D4 + d] = f2b4(w1); vb[2 * D4 + d] = f2b4(w2); vb[3 * D4 + d] = f2b4(w3);
        s0 += mm.x * w0.x + mm.y * w0.y + mm.z * w0.z + mm.w * w0.w;
        s1 += mm.x * w1.x + mm.y * w1.y + mm.z * w1.z + mm.w * w1.w;
        s2 += mm.x * w2.x + mm.y * w2.y + mm.z * w2.z + mm.w * w2.w;
        s3 += mm.x * w3.x + mm.y * w3.y + mm.z * w3.z + mm.w * w3.w;
    }
    float r;
    r = block_sum(sm, red); if (tid == 0) msq[n] = r;
    r = block_sum(s0, red); if (tid == 0) c[n * 4 + 0] = r;
    r = block_sum(s1, red); if (tid == 0) c[n * 4 + 1] = r;
    r = block_sum(s2, red); if (tid == 0) c[n * 4 + 2] = r;
    r = block_sum(s3, red); if (tid == 0) c[n * 4 + 3] = r;
}

// per-row: bf16 convert x + xsq[b] (float4)
__global__ void prep_x(const float4* __restrict__ X, ushort4* __restrict__ Xbf,
                       float* __restrict__ out, int D4) {
    __shared__ float red[4];
    int b = blockIdx.x, tid = threadIdx.x;
    const float4* row = X + (long)b * D4;
    ushort4* rb = Xbf + (long)b * D4;
    float s = 0;
    for (int d = tid; d < D4; d += 256) {
        float4 f = row[d];
        rb[d] = f2b4(f);
        s += f.x * f.x + f.y * f.y + f.z * f.z + f.w * f.w;
    }
    float r = block_sum(s, red);
    if (tid == 0) out[b] = r;
}

// ---------------- batchnorm ----------------
__global__ void bn_finalize(const double* __restrict__ sums, const double* __restrict__ sumsq,
                            const float* __restrict__ g, const float* __restrict__ b,
                            float* __restrict__ scale, float* __restrict__ shift) {
    int c = blockIdx.x * 256 + threadIdx.x;
    double m = sums[c] * (1.0 / BATCH);
    double var = sumsq[c] * (1.0 / BATCH) - m * m;
    float inv = (float)(1.0 / sqrt(var + (double)BN_EPS));
    float sc = g[c] * inv;
    scale[c] = sc;
    shift[c] = b[c] - (float)m * sc;
}

// stage1 apply: in-place BN + bf16 copy + per-row sum-of-squares (float4)
__global__ void bn_apply1(float4* __restrict__ X, ushort4* __restrict__ Xbf,
                          float* __restrict__ fsq, const float4* __restrict__ scale,
                          const float4* __restrict__ shift) {
    __shared__ float red[4];
    int b = blockIdx.x, tid = threadIdx.x;
    float4* row = X + (long)b * (N_H / 4);
    ushort4* rb = Xbf + (long)b * (N_H / 4);
    float s = 0;
    for (int c = tid; c < N_H / 4; c += 256) {
        float4 xv = row[c], sc = scale[c], sh = shift[c];
        float4 y;
        y.x = xv.x * sc.x + sh.x; y.y = xv.y * sc.y + sh.y;
        y.z = xv.z * sc.z + sh.z; y.w = xv.w * sc.w + sh.w;
        row[c] = y;
        rb[c] = f2b4(y);
        s += y.x * y.x + y.y * y.y + y.z * y.z + y.w * y.w;
    }
    float r = block_sum(s, red);
    if (tid == 0) fsq[b] = r;
}

// stage2 apply: BN + relu, write both fp32 output slots + bf16 copy (float4)
__global__ void bn_apply2(float4* __restrict__ X, float4* __restrict__ X2,
                          ushort4* __restrict__ Xbf,
                          const float4* __restrict__ scale, const float4* __restrict__ shift) {
    int b = blockIdx.x, tid = threadIdx.x;
    float4* row = X + (long)b * (N_H / 4);
    float4* row2 = X2 + (long)b * (N_H / 4);
    ushort4* rb = Xbf + (long)b * (N_H / 4);
    for (int c = tid; c < N_H / 4; c += 256) {
        float4 xv = row[c], sc = scale[c], sh = shift[c];
        float4 y;
        y.x = fmaxf(xv.x * sc.x + sh.x, 0.f); y.y = fmaxf(xv.y * sc.y + sh.y, 0.f);
        y.z = fmaxf(xv.z * sc.z + sh.z, 0.f); y.w = fmaxf(xv.w * sc.w + sh.w, 0.f);
        row[c] = y;
        row2[c] = y;
        rb[c] = f2b4(y);
    }
}

// ---------------- GEMM core: 128x128 tile, BK=64 (32 MFMA per barrier), 4 waves 2x2 ----
// LDS rows are 64 bf16 = 128 B = 8 chunks of 16 B. Chunk slot s of row r holds global
// chunk s ^ (r&7) (XOR swizzle; conflict-free reads, every 8-lane phase covers all 8
// bank-quads once). Staging source stays within each row's contiguous 128 B so global
// coalescing is preserved; global_load_lds dst is wave-contiguous (c*16B).
// BK=64 halves the per-tile barrier count vs BK=32 — the vmcnt(0)+s_barrier drain is
// the measured bottleneck (R2: MfmaUtil 23% with ZERO bank conflicts).
__device__ __forceinline__ void gemm_tile(const short* __restrict__ A, const short* __restrict__ B,
                                          int K, short* As, short* Bs, f32x4 acc[4][4]) {
    const int tid = threadIdx.x;
    const int lane = tid & 63, wave = tid >> 6;
    const int wm = wave & 1, wn = wave >> 1;
    const int lr = lane & 15, lq = lane >> 4;

    const short* ga[4]; const short* gb[4];
    short* la[4]; short* lb[4];
    #pragma unroll
    for (int p = 0; p < 4; ++p) {
        int c = tid + 256 * p;
        int row = c >> 3, slot = c & 7;
        int g = slot ^ (row & 7);
        ga[p] = A + (long)row * K + g * 8;
        gb[p] = B + (long)row * K + g * 8;
        la[p] = As + c * 8;
        lb[p] = Bs + c * 8;
    }

    const int s0 = (lq ^ (lr & 7)) * 8;                 // shorts offset of ks=0 chunk
    const short* paBase = As + (wm * 64 + lr) * 64;
    const short* pbBase = Bs + (wn * 64 + lr) * 64;

    for (int kt = 0; kt < K; kt += 64) {
        #pragma unroll
        for (int p = 0; p < 4; ++p) async16(ga[p], la[p]);
        #pragma unroll
        for (int p = 0; p < 4; ++p) async16(gb[p], lb[p]);
        #pragma unroll
        for (int p = 0; p < 4; ++p) { ga[p] += 64; gb[p] += 64; }
        __syncthreads();
        #pragma unroll
        for (int ks = 0; ks < 2; ++ks) {
            const int so = s0 ^ (ks * 32);              // chunk ^= 4  (16B = 8 shorts; 4*8=32)
            bf16x8 af[4], bfr[4];
            #pragma unroll
            for (int i = 0; i < 4; i++) {
                af[i]  = *(const bf16x8*)(paBase + i * 1024 + so);
                bfr[i] = *(const bf16x8*)(pbBase + i * 1024 + so);
            }
            #pragma unroll
            for (int i = 0; i < 4; i++)
                #pragma unroll
                for (int j = 0; j < 4; j++)
                    acc[i][j] = __builtin_amdgcn_mfma_f32_16x16x32_bf16(af[i], bfr[j], acc[i][j], 0, 0, 0);
        }
        __syncthreads();
    }
}

// S-GEMM: quadS[b,n] = lam[n]*(rsq[b] - 2*(A.B^T)[b,n] + msq[n])
__global__ __launch_bounds__(256) void gemm_s(const short* __restrict__ A, const short* __restrict__ B,
                                              float* __restrict__ quadS, const float* __restrict__ rsq,
                                              const float* __restrict__ msq, const float* __restrict__ lam,
                                              int K, int N) {
    __shared__ short As[128 * 64];
    __shared__ short Bs[128 * 64];
    int m0 = blockIdx.y * 128, n0 = blockIdx.x * 128;
    f32x4 acc[4][4];
    #pragma unroll
    for (int i = 0; i < 4; i++)
        #pragma unroll
        for (int j = 0; j < 4; j++) acc[i][j] = zero4();
    gemm_tile(A + (long)m0 * K, B + (long)n0 * K, K, As, Bs, acc);

    const int lane = threadIdx.x & 63, wave = threadIdx.x >> 6;
    const int wm = wave & 1, wn = wave >> 1, lr = lane & 15, lq = lane >> 4;
    #pragma unroll
    for (int j = 0; j < 4; j++) {
        int col = n0 + wn * 64 + j * 16 + lr;
        float lamc = lam[col], msqc = msq[col];
        #pragma unroll
        for (int i = 0; i < 4; i++) {
            int rowb = m0 + wm * 64 + i * 16 + lq * 4;
            #pragma unroll
            for (int r = 0; r < 4; r++) {
                int row = rowb + r;
                quadS[(long)row * N + col] = lamc * (rsq[row] - 2.0f * acc[i][j][r] + msqc);
            }
        }
    }
}

// P-GEMM: proj[b,j] = (A.B^T)[b,j] - c[j];  q = quadS[b,n] + sum_k proj^2
// DO_EXP=0: out = -q   DO_EXP=1: out = exp(-q/2048)
// BN partial sums fused; lq-reduced via shfl (4x fewer f64 atomics than R2).
template <int DO_EXP>
__global__ __launch_bounds__(256) void gemm_p(const short* __restrict__ A, const short* __restrict__ B,
                                              const float* __restrict__ quadS, const float* __restrict__ cvec,
                                              float* __restrict__ out, double* __restrict__ sums,
                                              double* __restrict__ sumsq, int K) {
    __shared__ short As[128 * 64];
    __shared__ short Bs[128 * 64];
    int m0 = blockIdx.y * 128, n0 = blockIdx.x * 128;
    f32x4 acc[4][4];
    #pragma unroll
    for (int i = 0; i < 4; i++)
        #pragma unroll
        for (int j = 0; j < 4; j++) acc[i][j] = zero4();
    gemm_tile(A + (long)m0 * K, B + (long)n0 * K, K, As, Bs, acc);

    const int lane = threadIdx.x & 63, wave = threadIdx.x >> 6;
    const int wm = wave & 1, wn = wave >> 1, lr = lane & 15, lq = lane >> 4;
    #pragma unroll
    for (int j = 0; j < 4; j++) {
        int col = n0 + wn * 64 + j * 16 + lr;      // col in [0,8192) = n*4+k
        float cc = cvec[col];
        double lsum = 0.0, lsq = 0.0;
        int n = col >> 2;
        #pragma unroll
        for (int i = 0; i < 4; i++) {
            int rowb = m0 + wm * 64 + i * 16 + lq * 4;
            #pragma unroll
            for (int r = 0; r < 4; r++) {
                float d = acc[i][j][r] - cc;
                float s = d * d;
                s += __shfl_xor(s, 1);
                s += __shfl_xor(s, 2);
                if ((lane & 3) == 0) {
                    int row = rowb + r;
                    float q = quadS[(long)row * N_H + n] + s;
                    float val = DO_EXP ? __expf(-q * (1.0f / 2048.0f)) : -q;
                    out[(long)row * N_H + n] = val;
                    lsum += val;
                    lsq += (double)val * val;
                }
            }
        }
        // lanes differing only in lq hold partials for the SAME column n (different rows)
        lsum += __shfl_xor(lsum, 16); lsum += __shfl_xor(lsum, 32);
        lsq  += __shfl_xor(lsq, 16);  lsq  += __shfl_xor(lsq, 32);
        if (lane < 16 && (lane & 3) == 0) {
            atomicAdd(&sums[n], lsum);
            atomicAdd(&sumsq[n], lsq);
        }
    }
}

// logits GEMM: out[b,j] = (A.B^T)[b,j] + bias[j], j < 1000
__global__ __launch_bounds__(256) void gemm_lin(const short* __restrict__ A, const short* __restrict__ B,
                                                const float* __restrict__ bias, float* __restrict__ out,
                                                int K) {
    __shared__ short As[128 * 64];
    __shared__ short Bs[128 * 64];
    int m0 = blockIdx.y * 128, n0 = blockIdx.x * 128;
    f32x4 acc[4][4];
    #pragma unroll
    for (int i = 0; i < 4; i++)
        #pragma unroll
        for (int j = 0; j < 4; j++) acc[i][j] = zero4();
    gemm_tile(A + (long)m0 * K, B + (long)n0 * K, K, As, Bs, acc);

    const int lane = threadIdx.x & 63, wave = threadIdx.x >> 6;
    const int wm = wave & 1, wn = wave >> 1, lr = lane & 15, lq = lane >> 4;
    #pragma unroll
    for (int j = 0; j < 4; j++) {
        int col = n0 + wn * 64 + j * 16 + lr;
        float bb = (col < N_CLS) ? bias[col] : 0.f;
        #pragma unroll
        for (int i = 0; i < 4; i++) {
            int rowb = m0 + wm * 64 + i * 16 + lq * 4;
            #pragma unroll
            for (int r = 0; r < 4; r++) {
                if (col < N_CLS) {
                    int row = rowb + r;
                    out[(long)row * N_CLS + col] = acc[i][j][r] + bb;
                }
            }
        }
    }
}

extern "C" void kernel_launch(void* const* d_in, const int* in_sizes, int n_in,
                              void* d_out, int out_size, void* d_ws, size_t ws_size,
                              hipStream_t stream) {
    const float* x   = (const float*)d_in[0];
    const float* mu1 = (const float*)d_in[1];
    const float* lam1= (const float*)d_in[2];
    const float* v1  = (const float*)d_in[3];
    const float* g1  = (const float*)d_in[4];
    const float* b1  = (const float*)d_in[5];
    const float* mu2 = (const float*)d_in[6];
    const float* lam2= (const float*)d_in[7];
    const float* v2  = (const float*)d_in[8];
    const float* g2  = (const float*)d_in[9];
    const float* b2  = (const float*)d_in[10];
    const float* Wl  = (const float*)d_in[11];
    const float* bl  = (const float*)d_in[12];

    float* out = (float*)d_out;
    float* logits = out;                                   // 8192*1000
    float* feat1  = out + (long)BATCH * N_CLS;             // 8192*2048
    float* feat2a = feat1 + (long)BATCH * N_H;             // 8192*2048
    float* feat2b = feat2a + (long)BATCH * N_H;            // 8192*2048 (written last)
    float* quadS  = feat2b;                                // scratch until bn_apply2
                                                           // (strict write-before-read
                                                           // each launch -> poison-safe)

    // ---- workspace: lifetime-aliased regions ----
    // Previous layout needed ~151.5 MB and ignored ws_size; writes past the end of the
    // workspace corrupted neighboring allocations (post-timing divergence with passing
    // fresh-vs-graph tripwire = persistent-state corruption). Buffer lifetimes are
    // disjoint, so alias:
    //   Region A (36 MB): x_bf|mu1_bf|v1_bf (stage-1 operands, dead after gemm_p<0>)
    //                     -> reused as f1_bf (32 MB, born in bn_apply1)
    //   Region B (40 MB): mu2_bf|v2_bf (stage-2 operands, dead after gemm_p<1>)
    //                     -> reused as f2_bf (32 MB, born in bn_apply2)
    //   wl_bf (4 MB) stays live to the end -> separate.
    // Total: ~80.4 MB.
    char* w = (char*)d_ws;
    size_t off = 0;
    auto alloc = [&](size_t bytes) -> void* {
        void* p = w + off;
        off += (bytes + 255) & ~(size_t)255;
        return p;
    };
    const size_t SZ_XBF  = (size_t)BATCH * D_IN * 2;        // 16 MB
    const size_t SZ_MU1  = (size_t)N_H * D_IN * 2;          //  4 MB
    const size_t SZ_V1   = (size_t)N_H * 4 * D_IN * 2;      // 16 MB
    const size_t SZ_MU2  = (size_t)N_H * N_H * 2;           //  8 MB
    const size_t SZ_V2   = (size_t)N_H * 4 * N_H * 2;       // 32 MB

    char* regionA = (char*)alloc(SZ_XBF + SZ_MU1 + SZ_V1);  // 36 MB
    char* regionB = (char*)alloc(SZ_MU2 + SZ_V2);           // 40 MB
    short* x_bf   = (short*)(regionA);
    short* mu1_bf = (short*)(regionA + SZ_XBF);
    short* v1_bf  = (short*)(regionA + SZ_XBF + SZ_MU1);
    short* f1_bf  = (short*)(regionA);                      // 32 MB, aliases stage-1 operands
    short* mu2_bf = (short*)(regionB);
    short* v2_bf  = (short*)(regionB + SZ_MU2);
    short* f2_bf  = (short*)(regionB);                      // 32 MB, aliases stage-2 operands
    short* wl_bf  = (short*)alloc((size_t)1024 * N_H * 2);  //  4 MB, live to the end
    float* xsq    = (float*)alloc(BATCH * 4);
    float* fsq    = (float*)alloc(BATCH * 4);
    float* msq1   = (float*)alloc(N_H * 4);
    float* c1     = (float*)alloc(N_H * 4 * 4);
    float* msq2   = (float*)alloc(N_H * 4);
    float* c2     = (float*)alloc(N_H * 4 * 4);
    double* sums1 = (double*)alloc(N_H * 8 * 4);           // sums1|sumsq1|sums2|sumsq2
    double* sumsq1 = sums1 + N_H;
    double* sums2  = sums1 + 2 * N_H;
    double* sumsq2 = sums1 + 3 * N_H;
    float* scale1 = (float*)alloc(N_H * 4);
    float* shift1 = (float*)alloc(N_H * 4);
    float* scale2 = (float*)alloc(N_H * 4);
    float* shift2 = (float*)alloc(N_H * 4);

    (void)in_sizes; (void)n_in; (void)out_size; (void)ws_size;

    // ---- prep: fused conversions & reductions ----
    hipMemsetAsync(sums1, 0, N_H * 8 * 4, stream);
    prep_x<<<BATCH, 256, 0, stream>>>((const float4*)x, (ushort4*)x_bf, xsq, D_IN / 4);
    prep_nv<<<N_H, 256, 0, stream>>>((const float4*)mu1, (const float4*)v1, (ushort4*)mu1_bf, (ushort4*)v1_bf, msq1, c1, D_IN / 4);
    prep_nv<<<N_H, 256, 0, stream>>>((const float4*)mu2, (const float4*)v2, (ushort4*)mu2_bf, (ushort4*)v2_bf, msq2, c2, N_H / 4);
    cvt_wl<<<(1024 * (N_H / 4)) / 256, 256, 0, stream>>>((const float4*)Wl, (ushort4*)wl_bf);

    // ---- stage 1: quad1 -> out1 = -quad1 (into feat1 slot), BN1 sums fused ----
    gemm_s<<<dim3(N_H / 128, BATCH / 128), 256, 0, stream>>>(x_bf, mu1_bf, quadS, xsq, msq1, lam1, D_IN, N_H);
    gemm_p<0><<<dim3((N_H * 4) / 128, BATCH / 128), 256, 0, stream>>>(x_bf, v1_bf, quadS, c1, feat1, sums1, sumsq1, D_IN);

    // ---- BN1 (bn_apply1 writes f1_bf over the now-dead stage-1 operands) ----
    bn_finalize<<<N_H / 256, 256, 0, stream>>>(sums1, sumsq1, g1, b1, scale1, shift1);
    bn_apply1<<<BATCH, 256, 0, stream>>>((float4*)feat1, (ushort4*)f1_bf, fsq, (const float4*)scale1, (const float4*)shift1);

    // ---- stage 2: quad2 -> out2 = exp(-quad2/2048) (into feat2a slot), BN2 sums fused ----
    gemm_s<<<dim3(N_H / 128, BATCH / 128), 256, 0, stream>>>(f1_bf, mu2_bf, quadS, fsq, msq2, lam2, N_H, N_H);
    gemm_p<1><<<dim3((N_H * 4) / 128, BATCH / 128), 256, 0, stream>>>(f1_bf, v2_bf, quadS, c2, feat2a, sums2, sumsq2, N_H);

    // ---- BN2 + relu (fills feat2b, overwriting quadS scratch; writes f2_bf over
    //      the now-dead stage-2 operands) ----
    bn_finalize<<<N_H / 256, 256, 0, stream>>>(sums2, sumsq2, g2, b2, scale2, shift2);
    bn_apply2<<<BATCH, 256, 0, stream>>>((float4*)feat2a, (float4*)feat2b, (ushort4*)f2_bf, (const float4*)scale2, (const float4*)shift2);

    // ---- logits ----
    gemm_lin<<<dim3(1024 / 128, BATCH / 128), 256, 0, stream>>>(f2_bf, wl_bf, bl, logits, N_H);
}

// Round 2
// 1209.779 us; speedup vs baseline: 1.1204x; 1.1204x over previous
//
#include <hip/hip_runtime.h>
#include <hip/hip_bf16.h>

typedef __attribute__((ext_vector_type(8))) short bf16x8;
typedef __attribute__((ext_vector_type(4))) float f32x4;

#define BATCH 8192
#define D_IN 1024
#define N_H 2048
#define N_CLS 1000
#define BN_EPS 1e-5f

__device__ __forceinline__ f32x4 zero4() { f32x4 z; z.x = 0.f; z.y = 0.f; z.z = 0.f; z.w = 0.f; return z; }

__device__ __forceinline__ unsigned short f2b(float x) {
    unsigned u = __float_as_uint(x);
    u += 0x7fff + ((u >> 16) & 1);   // round-to-nearest-even bf16
    return (unsigned short)(u >> 16);
}

__device__ __forceinline__ ushort4 f2b4(float4 f) {
    ushort4 o; o.x = f2b(f.x); o.y = f2b(f.y); o.z = f2b(f.z); o.w = f2b(f.w); return o;
}

__device__ __forceinline__ void async16(const void* g, void* l) {
    __builtin_amdgcn_global_load_lds((const __attribute__((address_space(1))) void*)g,
                                     (__attribute__((address_space(3))) void*)l, 16, 0, 0);
}

// Wl (1000x2048) -> bf16 padded to (1024x2048)
__global__ void cvt_wl(const float4* __restrict__ in, ushort4* __restrict__ out) {
    long i = (long)blockIdx.x * 256 + threadIdx.x;
    int j = (int)(i >> 9);
    ushort4 o; o.x = 0; o.y = 0; o.z = 0; o.w = 0;
    if (j < N_CLS) o = f2b4(in[i]);
    out[i] = o;
}

// ---------------- reductions ----------------
__device__ __forceinline__ float block_sum(float v, float* red) {
    #pragma unroll
    for (int off = 32; off > 0; off >>= 1) v += __shfl_down(v, off);
    __syncthreads();
    if ((threadIdx.x & 63) == 0) red[threadIdx.x >> 6] = v;
    __syncthreads();
    return red[0] + red[1] + red[2] + red[3];
}

// per-n: bf16 convert mu,v + msq[n]=mu.mu + c[n*4+k]=mu.v_k (fused cvt+dots, float4)
__global__ void prep_nv(const float4* __restrict__ mu, const float4* __restrict__ v,
                        ushort4* __restrict__ mu_bf, ushort4* __restrict__ v_bf,
                        float* __restrict__ msq, float* __restrict__ c, int D4) {
    __shared__ float red[4];
    int n = blockIdx.x, tid = threadIdx.x;
    const float4* m = mu + (long)n * D4;
    const float4* vv = v + (long)n * 4 * D4;
    ushort4* mb = mu_bf + (long)n * D4;
    ushort4* vb = v_bf + (long)n * 4 * D4;
    float sm = 0, s0 = 0, s1 = 0, s2 = 0, s3 = 0;
    for (int d = tid; d < D4; d += 256) {
        float4 mm = m[d];
        mb[d] = f2b4(mm);
        sm += mm.x * mm.x + mm.y * mm.y + mm.z * mm.z + mm.w * mm.w;
        float4 w0 = vv[d], w1 = vv[D4 + d], w2 = vv[2 * D4 + d], w3 = vv[3 * D4 + d];
        vb[d] = f2b4(w0); vb[D4 + d] = f2b4(w1); vb[2 * D4 + d] = f2b4(w2); vb[3 * D4 + d] = f2b4(w3);
        s0 += mm.x * w0.x + mm.y * w0.y + mm.z * w0.z + mm.w * w0.w;
        s1 += mm.x * w1.x + mm.y * w1.y + mm.z * w1.z + mm.w * w1.w;
        s2 += mm.x * w2.x + mm.y * w2.y + mm.z * w2.z + mm.w * w2.w;
        s3 += mm.x * w3.x + mm.y * w3.y + mm.z * w3.z + mm.w * w3.w;
    }
    float r;
    r = block_sum(sm, red); if (tid == 0) msq[n] = r;
    r = block_sum(s0, red); if (tid == 0) c[n * 4 + 0] = r;
    r = block_sum(s1, red); if (tid == 0) c[n * 4 + 1] = r;
    r = block_sum(s2, red); if (tid == 0) c[n * 4 + 2] = r;
    r = block_sum(s3, red); if (tid == 0) c[n * 4 + 3] = r;
}

// per-row: bf16 convert x + xsq[b] (float4)
__global__ void prep_x(const float4* __restrict__ X, ushort4* __restrict__ Xbf,
                       float* __restrict__ out, int D4) {
    __shared__ float red[4];
    int b = blockIdx.x, tid = threadIdx.x;
    const float4* row = X + (long)b * D4;
    ushort4* rb = Xbf + (long)b * D4;
    float s = 0;
    for (int d = tid; d < D4; d += 256) {
        float4 f = row[d];
        rb[d] = f2b4(f);
        s += f.x * f.x + f.y * f.y + f.z * f.z + f.w * f.w;
    }
    float r = block_sum(s, red);
    if (tid == 0) out[b] = r;
}

// ---------------- batchnorm ----------------
__global__ void bn_finalize(const double* __restrict__ sums, const double* __restrict__ sumsq,
                            const float* __restrict__ g, const float* __restrict__ b,
                            float* __restrict__ scale, float* __restrict__ shift) {
    int c = blockIdx.x * 256 + threadIdx.x;
    double m = sums[c] * (1.0 / BATCH);
    double var = sumsq[c] * (1.0 / BATCH) - m * m;
    float inv = (float)(1.0 / sqrt(var + (double)BN_EPS));
    float sc = g[c] * inv;
    scale[c] = sc;
    shift[c] = b[c] - (float)m * sc;
}

// stage1 apply: in-place BN + bf16 copy + per-row sum-of-squares (float4)
__global__ void bn_apply1(float4* __restrict__ X, ushort4* __restrict__ Xbf,
                          float* __restrict__ fsq, const float4* __restrict__ scale,
                          const float4* __restrict__ shift) {
    __shared__ float red[4];
    int b = blockIdx.x, tid = threadIdx.x;
    float4* row = X + (long)b * (N_H / 4);
    ushort4* rb = Xbf + (long)b * (N_H / 4);
    float s = 0;
    for (int c = tid; c < N_H / 4; c += 256) {
        float4 xv = row[c], sc = scale[c], sh = shift[c];
        float4 y;
        y.x = xv.x * sc.x + sh.x; y.y = xv.y * sc.y + sh.y;
        y.z = xv.z * sc.z + sh.z; y.w = xv.w * sc.w + sh.w;
        row[c] = y;
        rb[c] = f2b4(y);
        s += y.x * y.x + y.y * y.y + y.z * y.z + y.w * y.w;
    }
    float r = block_sum(s, red);
    if (tid == 0) fsq[b] = r;
}

// stage2 apply: BN + relu, write both fp32 output slots + bf16 copy (float4)
__global__ void bn_apply2(float4* __restrict__ X, float4* __restrict__ X2,
                          ushort4* __restrict__ Xbf,
                          const float4* __restrict__ scale, const float4* __restrict__ shift) {
    int b = blockIdx.x, tid = threadIdx.x;
    float4* row = X + (long)b * (N_H / 4);
    float4* row2 = X2 + (long)b * (N_H / 4);
    ushort4* rb = Xbf + (long)b * (N_H / 4);
    for (int c = tid; c < N_H / 4; c += 256) {
        float4 xv = row[c], sc = scale[c], sh = shift[c];
        float4 y;
        y.x = fmaxf(xv.x * sc.x + sh.x, 0.f); y.y = fmaxf(xv.y * sc.y + sh.y, 0.f);
        y.z = fmaxf(xv.z * sc.z + sh.z, 0.f); y.w = fmaxf(xv.w * sc.w + sh.w, 0.f);
        row[c] = y;
        row2[c] = y;
        rb[c] = f2b4(y);
    }
}

// ---------------- GEMM core: 128x128 tile, BK=64, 4 waves 2x2, 2-PHASE PIPELINE ----
// R2 counters: MfmaUtil 24.6%, HBM 10%, bank-conflict 0, occupancy ~2 blocks/CU ->
// latency-bound on the per-K-step vmcnt(0)+barrier drain (loads issued then
// immediately barrier-waited; zero intra-block overlap).
// Fix (T3 minimum 2-phase, learn_hip m230/m248): double-buffered LDS, ONE
// __syncthreads per K-step: stage(next) -> ds_read+MFMA(cur) -> sync. Tile t+1's
// global_load_lds latency hides under tile t's 32 MFMAs.
// Codegen notes:
//  - FOUR SEPARATE __shared__ objects (no runtime buffer index): LLVM AA can prove
//    ds_read(buf0) doesn't alias in-flight global_load_lds writes to buf1, so no
//    spurious vmcnt(0) lands before the reads (and no rule#20 scratch).
//  - No inline-asm waits: __syncthreads() emits exactly the vmcnt(0)+s_barrier the
//    recipe needs at depth-1 prefetch (avoids the rule#18 MFMA-hoist hazard).
// XOR swizzle unchanged: chunk slot s of row r holds global chunk s^(r&7);
// reads stay conflict-free, staging dst stays wave-contiguous (c*16B).
__device__ __forceinline__ void gemm_tile(const short* __restrict__ A, const short* __restrict__ B,
                                          int K, f32x4 acc[4][4]) {
    __shared__ short As0[128 * 64];
    __shared__ short Bs0[128 * 64];
    __shared__ short As1[128 * 64];
    __shared__ short Bs1[128 * 64];

    const int tid = threadIdx.x;
    const int lane = tid & 63;
    const int wm = (tid >> 6) & 1, wn = tid >> 7;
    const int lr = lane & 15, lq = lane >> 4;

    const short* ga[4]; const short* gb[4];
    int lo[4];
    #pragma unroll
    for (int p = 0; p < 4; ++p) {
        int c = tid + 256 * p;
        int row = c >> 3, slot = c & 7;
        int g = slot ^ (row & 7);
        ga[p] = A + (long)row * K + g * 8;
        gb[p] = B + (long)row * K + g * 8;
        lo[p] = c * 8;
    }
    const int s0 = (lq ^ (lr & 7)) * 8;                 // shorts offset of ks=0 chunk

    auto stage = [&](short* Asb, short* Bsb) {
        #pragma unroll
        for (int p = 0; p < 4; ++p) async16(ga[p], Asb + lo[p]);
        #pragma unroll
        for (int p = 0; p < 4; ++p) async16(gb[p], Bsb + lo[p]);
        #pragma unroll
        for (int p = 0; p < 4; ++p) { ga[p] += 64; gb[p] += 64; }
    };
    auto compute = [&](const short* Asb, const short* Bsb) {
        const short* pa = Asb + (wm * 64 + lr) * 64;
        const short* pb = Bsb + (wn * 64 + lr) * 64;
        #pragma unroll
        for (int ks = 0; ks < 2; ++ks) {
            const int so = s0 ^ (ks * 32);              // chunk ^= 4 (16B = 8 shorts)
            bf16x8 af[4], bfr[4];
            #pragma unroll
            for (int i = 0; i < 4; i++) {
                af[i]  = *(const bf16x8*)(pa + i * 1024 + so);
                bfr[i] = *(const bf16x8*)(pb + i * 1024 + so);
            }
            __builtin_amdgcn_s_setprio(1);
            #pragma unroll
            for (int i = 0; i < 4; i++)
                #pragma unroll
                for (int j = 0; j < 4; j++)
                    acc[i][j] = __builtin_amdgcn_mfma_f32_16x16x32_bf16(af[i], bfr[j], acc[i][j], 0, 0, 0);
            __builtin_amdgcn_s_setprio(0);
        }
    };

    const int NT = K >> 6;              // K/64: 16 or 32 here (always even, >= 4)
    stage(As0, Bs0);
    __syncthreads();                    // vmcnt(0)+barrier: tile 0 resident
    for (int t = 0; t < NT / 2 - 1; ++t) {
        stage(As1, Bs1);                // issue tile 2t+1 (flies under compute)
        compute(As0, Bs0);              // consume tile 2t
        __syncthreads();                // drain tile 2t+1 loads; all reads of buf0 done
        stage(As0, Bs0);                // issue tile 2t+2
        compute(As1, Bs1);              // consume tile 2t+1
        __syncthreads();
    }
    stage(As1, Bs1);                    // issue tile NT-1
    compute(As0, Bs0);                  // consume tile NT-2
    __syncthreads();
    compute(As1, Bs1);                  // consume tile NT-1 (no trailing barrier needed)
}

// S-GEMM: quadS[b,n] = lam[n]*(rsq[b] - 2*(A.B^T)[b,n] + msq[n])
__global__ __launch_bounds__(256) void gemm_s(const short* __restrict__ A, const short* __restrict__ B,
                                              float* __restrict__ quadS, const float* __restrict__ rsq,
                                              const float* __restrict__ msq, const float* __restrict__ lam,
                                              int K, int N) {
    int m0 = blockIdx.y * 128, n0 = blockIdx.x * 128;
    f32x4 acc[4][4];
    #pragma unroll
    for (int i = 0; i < 4; i++)
        #pragma unroll
        for (int j = 0; j < 4; j++) acc[i][j] = zero4();
    gemm_tile(A + (long)m0 * K, B + (long)n0 * K, K, acc);

    const int lane = threadIdx.x & 63, wave = threadIdx.x >> 6;
    const int wm = wave & 1, wn = wave >> 1, lr = lane & 15, lq = lane >> 4;
    #pragma unroll
    for (int j = 0; j < 4; j++) {
        int col = n0 + wn * 64 + j * 16 + lr;
        float lamc = lam[col], msqc = msq[col];
        #pragma unroll
        for (int i = 0; i < 4; i++) {
            int rowb = m0 + wm * 64 + i * 16 + lq * 4;
            #pragma unroll
            for (int r = 0; r < 4; r++) {
                int row = rowb + r;
                quadS[(long)row * N + col] = lamc * (rsq[row] - 2.0f * acc[i][j][r] + msqc);
            }
        }
    }
}

// P-GEMM: proj[b,j] = (A.B^T)[b,j] - c[j];  q = quadS[b,n] + sum_k proj^2
// DO_EXP=0: out = -q   DO_EXP=1: out = exp(-q/2048)
// BN partial sums fused; lq-reduced via shfl.
template <int DO_EXP>
__global__ __launch_bounds__(256) void gemm_p(const short* __restrict__ A, const short* __restrict__ B,
                                              const float* __restrict__ quadS, const float* __restrict__ cvec,
                                              float* __restrict__ out, double* __restrict__ sums,
                                              double* __restrict__ sumsq, int K) {
    int m0 = blockIdx.y * 128, n0 = blockIdx.x * 128;
    f32x4 acc[4][4];
    #pragma unroll
    for (int i = 0; i < 4; i++)
        #pragma unroll
        for (int j = 0; j < 4; j++) acc[i][j] = zero4();
    gemm_tile(A + (long)m0 * K, B + (long)n0 * K, K, acc);

    const int lane = threadIdx.x & 63, wave = threadIdx.x >> 6;
    const int wm = wave & 1, wn = wave >> 1, lr = lane & 15, lq = lane >> 4;
    #pragma unroll
    for (int j = 0; j < 4; j++) {
        int col = n0 + wn * 64 + j * 16 + lr;      // col in [0,8192) = n*4+k
        float cc = cvec[col];
        double lsum = 0.0, lsq = 0.0;
        int n = col >> 2;
        #pragma unroll
        for (int i = 0; i < 4; i++) {
            int rowb = m0 + wm * 64 + i * 16 + lq * 4;
            #pragma unroll
            for (int r = 0; r < 4; r++) {
                float d = acc[i][j][r] - cc;
                float s = d * d;
                s += __shfl_xor(s, 1);
                s += __shfl_xor(s, 2);
                if ((lane & 3) == 0) {
                    int row = rowb + r;
                    float q = quadS[(long)row * N_H + n] + s;
                    float val = DO_EXP ? __expf(-q * (1.0f / 2048.0f)) : -q;
                    out[(long)row * N_H + n] = val;
                    lsum += val;
                    lsq += (double)val * val;
                }
            }
        }
        // lanes differing only in lq hold partials for the SAME column n (different rows)
        lsum += __shfl_xor(lsum, 16); lsum += __shfl_xor(lsum, 32);
        lsq  += __shfl_xor(lsq, 16);  lsq  += __shfl_xor(lsq, 32);
        if (lane < 16 && (lane & 3) == 0) {
            atomicAdd(&sums[n], lsum);
            atomicAdd(&sumsq[n], lsq);
        }
    }
}

// logits GEMM: out[b,j] = (A.B^T)[b,j] + bias[j], j < 1000
__global__ __launch_bounds__(256) void gemm_lin(const short* __restrict__ A, const short* __restrict__ B,
                                                const float* __restrict__ bias, float* __restrict__ out,
                                                int K) {
    int m0 = blockIdx.y * 128, n0 = blockIdx.x * 128;
    f32x4 acc[4][4];
    #pragma unroll
    for (int i = 0; i < 4; i++)
        #pragma unroll
        for (int j = 0; j < 4; j++) acc[i][j] = zero4();
    gemm_tile(A + (long)m0 * K, B + (long)n0 * K, K, acc);

    const int lane = threadIdx.x & 63, wave = threadIdx.x >> 6;
    const int wm = wave & 1, wn = wave >> 1, lr = lane & 15, lq = lane >> 4;
    #pragma unroll
    for (int j = 0; j < 4; j++) {
        int col = n0 + wn * 64 + j * 16 + lr;
        float bb = (col < N_CLS) ? bias[col] : 0.f;
        #pragma unroll
        for (int i = 0; i < 4; i++) {
            int rowb = m0 + wm * 64 + i * 16 + lq * 4;
            #pragma unroll
            for (int r = 0; r < 4; r++) {
                if (col < N_CLS) {
                    int row = rowb + r;
                    out[(long)row * N_CLS + col] = acc[i][j][r] + bb;
                }
            }
        }
    }
}

extern "C" void kernel_launch(void* const* d_in, const int* in_sizes, int n_in,
                              void* d_out, int out_size, void* d_ws, size_t ws_size,
                              hipStream_t stream) {
    const float* x   = (const float*)d_in[0];
    const float* mu1 = (const float*)d_in[1];
    const float* lam1= (const float*)d_in[2];
    const float* v1  = (const float*)d_in[3];
    const float* g1  = (const float*)d_in[4];
    const float* b1  = (const float*)d_in[5];
    const float* mu2 = (const float*)d_in[6];
    const float* lam2= (const float*)d_in[7];
    const float* v2  = (const float*)d_in[8];
    const float* g2  = (const float*)d_in[9];
    const float* b2  = (const float*)d_in[10];
    const float* Wl  = (const float*)d_in[11];
    const float* bl  = (const float*)d_in[12];

    float* out = (float*)d_out;
    float* logits = out;                                   // 8192*1000
    float* feat1  = out + (long)BATCH * N_CLS;             // 8192*2048
    float* feat2a = feat1 + (long)BATCH * N_H;             // 8192*2048
    float* feat2b = feat2a + (long)BATCH * N_H;            // 8192*2048 (written last)
    float* quadS  = feat2b;                                // scratch until bn_apply2
                                                           // (strict write-before-read
                                                           // each launch -> poison-safe)

    // ---- workspace: lifetime-aliased regions (~80.4 MB total) ----
    //   Region A (36 MB): x_bf|mu1_bf|v1_bf (dead after gemm_p<0>) -> f1_bf (32 MB)
    //   Region B (40 MB): mu2_bf|v2_bf (dead after gemm_p<1>)      -> f2_bf (32 MB)
    //   wl_bf (4 MB) stays live to the end -> separate.
    char* w = (char*)d_ws;
    size_t off = 0;
    auto alloc = [&](size_t bytes) -> void* {
        void* p = w + off;
        off += (bytes + 255) & ~(size_t)255;
        return p;
    };
    const size_t SZ_XBF  = (size_t)BATCH * D_IN * 2;        // 16 MB
    const size_t SZ_MU1  = (size_t)N_H * D_IN * 2;          //  4 MB
    const size_t SZ_V1   = (size_t)N_H * 4 * D_IN * 2;      // 16 MB
    const size_t SZ_MU2  = (size_t)N_H * N_H * 2;           //  8 MB
    const size_t SZ_V2   = (size_t)N_H * 4 * N_H * 2;       // 32 MB

    char* regionA = (char*)alloc(SZ_XBF + SZ_MU1 + SZ_V1);  // 36 MB
    char* regionB = (char*)alloc(SZ_MU2 + SZ_V2);           // 40 MB
    short* x_bf   = (short*)(regionA);
    short* mu1_bf = (short*)(regionA + SZ_XBF);
    short* v1_bf  = (short*)(regionA + SZ_XBF + SZ_MU1);
    short* f1_bf  = (short*)(regionA);                      // 32 MB, aliases stage-1 operands
    short* mu2_bf = (short*)(regionB);
    short* v2_bf  = (short*)(regionB + SZ_MU2);
    short* f2_bf  = (short*)(regionB);                      // 32 MB, aliases stage-2 operands
    short* wl_bf  = (short*)alloc((size_t)1024 * N_H * 2);  //  4 MB, live to the end
    float* xsq    = (float*)alloc(BATCH * 4);
    float* fsq    = (float*)alloc(BATCH * 4);
    float* msq1   = (float*)alloc(N_H * 4);
    float* c1     = (float*)alloc(N_H * 4 * 4);
    float* msq2   = (float*)alloc(N_H * 4);
    float* c2     = (float*)alloc(N_H * 4 * 4);
    double* sums1 = (double*)alloc(N_H * 8 * 4);           // sums1|sumsq1|sums2|sumsq2
    double* sumsq1 = sums1 + N_H;
    double* sums2  = sums1 + 2 * N_H;
    double* sumsq2 = sums1 + 3 * N_H;
    float* scale1 = (float*)alloc(N_H * 4);
    float* shift1 = (float*)alloc(N_H * 4);
    float* scale2 = (float*)alloc(N_H * 4);
    float* shift2 = (float*)alloc(N_H * 4);

    (void)in_sizes; (void)n_in; (void)out_size; (void)ws_size;

    // ---- prep: fused conversions & reductions ----
    hipMemsetAsync(sums1, 0, N_H * 8 * 4, stream);
    prep_x<<<BATCH, 256, 0, stream>>>((const float4*)x, (ushort4*)x_bf, xsq, D_IN / 4);
    prep_nv<<<N_H, 256, 0, stream>>>((const float4*)mu1, (const float4*)v1, (ushort4*)mu1_bf, (ushort4*)v1_bf, msq1, c1, D_IN / 4);
    prep_nv<<<N_H, 256, 0, stream>>>((const float4*)mu2, (const float4*)v2, (ushort4*)mu2_bf, (ushort4*)v2_bf, msq2, c2, N_H / 4);
    cvt_wl<<<(1024 * (N_H / 4)) / 256, 256, 0, stream>>>((const float4*)Wl, (ushort4*)wl_bf);

    // ---- stage 1: quad1 -> out1 = -quad1 (into feat1 slot), BN1 sums fused ----
    gemm_s<<<dim3(N_H / 128, BATCH / 128), 256, 0, stream>>>(x_bf, mu1_bf, quadS, xsq, msq1, lam1, D_IN, N_H);
    gemm_p<0><<<dim3((N_H * 4) / 128, BATCH / 128), 256, 0, stream>>>(x_bf, v1_bf, quadS, c1, feat1, sums1, sumsq1, D_IN);

    // ---- BN1 (bn_apply1 writes f1_bf over the now-dead stage-1 operands) ----
    bn_finalize<<<N_H / 256, 256, 0, stream>>>(sums1, sumsq1, g1, b1, scale1, shift1);
    bn_apply1<<<BATCH, 256, 0, stream>>>((float4*)feat1, (ushort4*)f1_bf, fsq, (const float4*)scale1, (const float4*)shift1);

    // ---- stage 2: quad2 -> out2 = exp(-quad2/2048) (into feat2a slot), BN2 sums fused ----
    gemm_s<<<dim3(N_H / 128, BATCH / 128), 256, 0, stream>>>(f1_bf, mu2_bf, quadS, fsq, msq2, lam2, N_H, N_H);
    gemm_p<1><<<dim3((N_H * 4) / 128, BATCH / 128), 256, 0, stream>>>(f1_bf, v2_bf, quadS, c2, feat2a, sums2, sumsq2, N_H);

    // ---- BN2 + relu (fills feat2b, overwriting quadS scratch; writes f2_bf over
    //      the now-dead stage-2 operands) ----
    bn_finalize<<<N_H / 256, 256, 0, stream>>>(sums2, sumsq2, g2, b2, scale2, shift2);
    bn_apply2<<<BATCH, 256, 0, stream>>>((float4*)feat2a, (float4*)feat2b, (ushort4*)f2_bf, (const float4*)scale2, (const float4*)shift2);

    // ---- logits ----
    gemm_lin<<<dim3(1024 / 128, BATCH / 128), 256, 0, stream>>>(f2_bf, wl_bf, bl, logits, N_H);
}